// Round 14
// baseline (74.861 us; speedup 1.0000x reference)
//
#include <hip/hip_runtime.h>
#include <hip/hip_bf16.h>
#include <math.h>

typedef __attribute__((ext_vector_type(8))) short short8;
typedef __attribute__((ext_vector_type(4))) float f32x4;

#define NB 8192
#define ND 256
#define LN2f 0.6931471805599453f

__device__ __forceinline__ float bf2f(ushort u) {
  unsigned int x = ((unsigned int)u) << 16;
  return __builtin_bit_cast(float, x);
}
__device__ __forceinline__ ushort f2bf(float x) {
  return __builtin_bit_cast(ushort, __float2bfloat16(x));
}
// prefix count of triangle tiles before row-tile rb (tiles (rb,cb): cb >= rb/2)
__device__ __forceinline__ int S_of(int rb) {
  int T = rb >> 1;
  int s = 64 * T - T * (T - 1);
  if (rb & 1) s += 32 - T;
  return s;
}
__device__ __forceinline__ int block_of(int nid) {
  return nid < 160 ? nid / 5 : 32 + (nid - 160) / 4;
}

// ---- prep (blocks<2048): norm+quantize+transpose+dbuf; (>=2048): classsum --
__global__ void prep_kernel(const float* __restrict__ h, const int* __restrict__ labels,
                            ushort* __restrict__ hs, ushort* __restrict__ hsK,
                            float* __restrict__ dbuf, float* __restrict__ Cs,
                            float* __restrict__ cntf) {
  const float SCALE = 1.0f / sqrtf(0.07f * LN2f);
  int tid = threadIdx.x, lane = tid & 63, wave = tid >> 6;
  if (blockIdx.x < 2048) {
    int r = blockIdx.x * 4 + wave;
    float4 v = reinterpret_cast<const float4*>(h + (size_t)r * ND)[lane];
    float ss = v.x * v.x + v.y * v.y + v.z * v.z + v.w * v.w;
#pragma unroll
    for (int d = 1; d <= 32; d <<= 1) ss += __shfl_xor(ss, d);
    float scale = SCALE / fmaxf(sqrtf(ss), 1e-12f);
    ushort4 o;
    o.x = f2bf(v.x * scale); o.y = f2bf(v.y * scale);
    o.z = f2bf(v.z * scale); o.w = f2bf(v.w * scale);
    reinterpret_cast<ushort4*>(hs + (size_t)r * ND)[lane] = o;
    *reinterpret_cast<ushort4*>(
        hsK + ((size_t)((r >> 7) * 32 + (lane >> 1)) * 128 + (r & 127)) * 8 +
        (lane & 1) * 4) = o;
    float qx = bf2f(o.x), qy = bf2f(o.y), qz = bf2f(o.z), qw = bf2f(o.w);
    float dd = qx * qx + qy * qy + qz * qz + qw * qw;
#pragma unroll
    for (int d = 1; d <= 32; d <<= 1) dd += __shfl_xor(dd, d);
    if (lane == 0) dbuf[r] = dd;
    return;
  }
  // ---- class sum for class c (deterministic scan order) ----
  __shared__ int list[256];
  __shared__ int wscan[4];
  __shared__ float foldc[4][256];
  int c = blockIdx.x - 2048;
  int base0 = tid * 32;
  int mycnt = 0;
  for (int i2 = 0; i2 < 32; ++i2) mycnt += (labels[base0 + i2] == c) ? 1 : 0;
  int inc = mycnt;
#pragma unroll
  for (int d = 1; d < 64; d <<= 1) {
    int v2 = __shfl_up(inc, d);
    if (lane >= d) inc += v2;
  }
  if (lane == 63) wscan[wave] = inc;
  __syncthreads();
  int wbase = 0, ntot = 0;
#pragma unroll
  for (int w = 0; w < 4; ++w) { wbase += (w < wave) ? wscan[w] : 0; ntot += wscan[w]; }
  int off = wbase + inc - mycnt;
  for (int i2 = 0; i2 < 32; ++i2) {
    int idx = base0 + i2;
    if (labels[idx] == c) list[off++] = idx;
  }
  __syncthreads();
  float4 acc = make_float4(0.f, 0.f, 0.f, 0.f);
  for (int k = wave; k < ntot; k += 4) {
    int r2 = list[k];
    float4 v = reinterpret_cast<const float4*>(h + (size_t)r2 * ND)[lane];
    float ss2 = v.x * v.x + v.y * v.y + v.z * v.z + v.w * v.w;
#pragma unroll
    for (int d = 1; d <= 32; d <<= 1) ss2 += __shfl_xor(ss2, d);
    float sc2 = SCALE / fmaxf(sqrtf(ss2), 1e-12f);
    acc.x += bf2f(f2bf(v.x * sc2));
    acc.y += bf2f(f2bf(v.y * sc2));
    acc.z += bf2f(f2bf(v.z * sc2));
    acc.w += bf2f(f2bf(v.w * sc2));
  }
  reinterpret_cast<float4*>(&foldc[wave][0])[lane] = acc;
  __syncthreads();
  if (wave == 0) {
    float4 a0 = reinterpret_cast<float4*>(&foldc[0][0])[lane];
    float4 a1 = reinterpret_cast<float4*>(&foldc[1][0])[lane];
    float4 a2 = reinterpret_cast<float4*>(&foldc[2][0])[lane];
    float4 a3 = reinterpret_cast<float4*>(&foldc[3][0])[lane];
    float4 s;
    s.x = a0.x + a1.x + a2.x + a3.x;
    s.y = a0.y + a1.y + a2.y + a3.y;
    s.z = a0.z + a1.z + a2.z + a3.z;
    s.w = a0.w + a1.w + a2.w + a3.w;
    reinterpret_cast<float4*>(Cs + (size_t)c * ND)[lane] = s;
  }
  if (tid == 0) cntf[c] = (float)ntot;
}

// full A panel (64KB, contiguous) for row-tile rb
__device__ __forceinline__ void stageAfull(ushort* lds, const ushort* __restrict__ hsK,
                                           int rb, int tid) {
  const ushort* gp = hsK + (size_t)rb * 4096 * 8;
#pragma unroll
  for (int i = 0; i < 8; ++i) {
    int U = i * 512 + tid;
    __builtin_amdgcn_global_load_lds(
        (const __attribute__((address_space(1))) unsigned int*)(gp + (size_t)U * 8),
        (__attribute__((address_space(3))) unsigned int*)(lds + (size_t)U * 8),
        16, 0, 0);
  }
}
// B chunk (32KB): 256 cols of col-tile cb, K64 chunk ch; LDS [ku8][row256]
__device__ __forceinline__ void stageB(ushort* lds, const ushort* __restrict__ hsK,
                                       int cb, int ch, int tid) {
#pragma unroll
  for (int i = 0; i < 4; ++i) {
    int U = i * 512 + tid;
    int ku = U >> 8, row = U & 255;
    int half = row >> 7, rl = row & 127;
    const ushort* gp =
        hsK + ((size_t)(cb * 2 + half) * 4096 + (ch * 8 + ku) * 128 + rl) * 8;
    __builtin_amdgcn_global_load_lds(
        (const __attribute__((address_space(1))) unsigned int*)gp,
        (__attribute__((address_space(3))) unsigned int*)(lds + (size_t)U * 8),
        16, 0, 0);
  }
}

// ---- main: 256 persistent blocks, consecutive triangle tiles ---------------
__global__ __launch_bounds__(512)
void main_kernel(const ushort* __restrict__ hsK,
                 float* __restrict__ rowseg, float* __restrict__ colpart2) {
  __shared__ ushort Abuf[32768];      // 64 KB: [ku32][row128][8]
  __shared__ ushort Bbuf[2][16384];   // 2 x 32 KB
  __shared__ float fold[8][64];
  int tid = threadIdx.x, lane = tid & 63, wave = tid >> 6;
  int g = lane >> 4, cl = lane & 15;
  int b = blockIdx.x;
  int nS = (b < 32) ? b * 5 : 160 + (b - 32) * 4;
  int nT = (b < 32) ? 5 : 4;

  int rb = 0;
  while (S_of(rb + 1) <= nS) ++rb;
  int cb = (rb >> 1) + (nS - S_of(rb));

  stageAfull(Abuf, hsK, rb, tid);
  stageB(&Bbuf[0][0], hsK, cb, 0, tid);
  __syncthreads();

  int wrow = (wave >> 2) * 64, wcol = (wave & 3) * 64;
  float sr[16];
#pragma unroll
  for (int i = 0; i < 16; ++i) sr[i] = 0.f;
  int cur = 0;

#pragma unroll 1
  for (int t = 0; t < nT; ++t) {
    int nrb = rb, ncb = cb + 1;
    bool nvalid = (t + 1 < nT);
    if (nvalid && (nS + t + 1) >= S_of(rb + 1)) { nrb = rb + 1; ncb = nrb >> 1; }

    f32x4 acc[4][4];
#pragma unroll
    for (int rf = 0; rf < 4; ++rf)
#pragma unroll
      for (int cf = 0; cf < 4; ++cf) acc[rf][cf] = (f32x4){0.f, 0.f, 0.f, 0.f};

#pragma unroll 1
    for (int ch = 0; ch < 4; ++ch) {
      if (ch < 3) stageB(&Bbuf[cur ^ 1][0], hsK, cb, ch + 1, tid);
      else if (nvalid) stageB(&Bbuf[cur ^ 1][0], hsK, ncb, 0, tid);
      const ushort* At = Abuf + ch * 8192;       // 8 ku * 128 rows * 8 ush
      const ushort* Bt = &Bbuf[cur][0];
#pragma unroll
      for (int ks = 0; ks < 2; ++ks) {
        short8 bfr[4];
#pragma unroll
        for (int cf = 0; cf < 4; ++cf)
          bfr[cf] = *reinterpret_cast<const short8*>(
              Bt + ((ks * 4 + g) * 256 + wcol + cf * 16 + cl) * 8);
#pragma unroll
        for (int rf = 0; rf < 4; ++rf) {
          short8 a = *reinterpret_cast<const short8*>(
              At + ((ks * 4 + g) * 128 + wrow + rf * 16 + cl) * 8);
#pragma unroll
          for (int cf = 0; cf < 4; ++cf)
            acc[rf][cf] = __builtin_amdgcn_mfma_f32_16x16x32_bf16(
                a, bfr[cf], acc[rf][cf], 0, 0, 0);
        }
      }
      if (ch < 3) { __syncthreads(); cur ^= 1; }
    }

    // per-tile epilogue (barrier-free): exp2, sr accumulate, col partials
    float cc[4] = {0.f, 0.f, 0.f, 0.f};
#pragma unroll
    for (int rf = 0; rf < 4; ++rf)
#pragma unroll
      for (int cf = 0; cf < 4; ++cf)
#pragma unroll
        for (int q = 0; q < 4; ++q) {
          float e = __builtin_amdgcn_exp2f(acc[rf][cf][q]);
          sr[rf * 4 + q] += e;
          cc[cf] += e;
        }
#pragma unroll
    for (int i = 0; i < 4; ++i) {
      cc[i] += __shfl_xor(cc[i], 16);
      cc[i] += __shfl_xor(cc[i], 32);
    }
    bool diagish = (cb == (rb >> 1));
    if (!diagish && g == 0) {
#pragma unroll
      for (int cf = 0; cf < 4; ++cf)
        colpart2[(size_t)(rb * 2 + (wave >> 2)) * NB + cb * 256 + wcol + cf * 16 + cl] =
            cc[cf];
    }

    bool segEnd = (!nvalid) || (nrb != rb);
    if (segEnd) {
#pragma unroll
      for (int i = 0; i < 16; ++i) {
#pragma unroll
        for (int d = 1; d <= 8; d <<= 1) sr[i] += __shfl_xor(sr[i], d);
      }
      if (cl == 0) {
#pragma unroll
        for (int rf = 0; rf < 4; ++rf)
#pragma unroll
          for (int q = 0; q < 4; ++q)
            fold[wave][rf * 16 + g * 4 + q] = sr[rf * 4 + q];
      }
      __syncthreads();                 // fold visible; Bbuf readers done
      if (tid < 128) {
        int half = tid >> 6, rl2 = tid & 63;
        float rv = fold[half * 4 + 0][rl2] + fold[half * 4 + 1][rl2] +
                   fold[half * 4 + 2][rl2] + fold[half * 4 + 3][rl2];
        int slot = b - block_of(S_of(rb));
        rowseg[((size_t)rb * 9 + slot) * 128 + tid] = rv;
      }
#pragma unroll
      for (int i = 0; i < 16; ++i) sr[i] = 0.f;
      if (nvalid && nrb != rb) stageAfull(Abuf, hsK, nrb, tid);
      __syncthreads();                 // A staged/drained; fold reads done
    } else {
      __syncthreads();                 // protect Bbuf + drain cross-tile prefetch
    }
    cur ^= 1;
    rb = nrb; cb = ncb;
  }
}

// ---- per-row loss ----------------------------------------------------------
__global__ void rowloss_kernel(const ushort* __restrict__ hs,
                               const int* __restrict__ labels,
                               const float* __restrict__ Cs,
                               const float* __restrict__ cntf,
                               const float* __restrict__ rowseg,
                               const float* __restrict__ colpart2,
                               const float* __restrict__ dbuf,
                               float2* __restrict__ rl) {
  int lane = threadIdx.x & 63, wave = threadIdx.x >> 6;
  int row = blockIdx.x * 4 + wave;
  int lbl = labels[row];
  ushort4 qb = reinterpret_cast<const ushort4*>(hs + (size_t)row * ND)[lane];
  float4 cv = reinterpret_cast<const float4*>(Cs + (size_t)lbl * ND)[lane];
  float dot = bf2f(qb.x) * cv.x + bf2f(qb.y) * cv.y +
              bf2f(qb.z) * cv.z + bf2f(qb.w) * cv.w;
#pragma unroll
  for (int d = 1; d <= 32; d <<= 1) dot += __shfl_xor(dot, d);

  int rb0 = row >> 7;                  // 128-row tile
  int cr = row >> 8;                   // 256-col tile
  int bF = block_of(S_of(rb0));
  int bL = block_of(S_of(rb0 + 1) - 1);
  int nseg = bL - bF + 1;
  float part = 0.f;
  if (lane < nseg) part += rowseg[((size_t)rb0 * 9 + lane) * 128 + (row & 127)];
  if (lane < 2 * cr)
    part += colpart2[(size_t)(lane * 2) * NB + row] +
            colpart2[(size_t)(lane * 2 + 1) * NB + row];
#pragma unroll
  for (int d = 1; d <= 32; d <<= 1) part += __shfl_xor(part, d);

  if (lane == 0) {
    float dself = dbuf[row];
    float s = part - (1.0f - 1e-8f) * __builtin_amdgcn_exp2f(dself);
    float denom2 = log2f(s);
    float Sp2 = dot - dself;
    float n = cntf[lbl] - 1.0f;
    float li = 0.f, val = 0.f;
    if (n > 0.5f) { li = -LN2f * (Sp2 - n * denom2) / n; val = 1.f; }
    rl[row] = make_float2(li, val);
  }
}

__global__ __launch_bounds__(1024)
void reduce_kernel(const float2* __restrict__ rl, float* __restrict__ out) {
  int t = threadIdx.x;
  float L = 0.f, V = 0.f;
  for (int r = t; r < NB; r += 1024) { float2 p = rl[r]; L += p.x; V += p.y; }
#pragma unroll
  for (int d = 1; d <= 32; d <<= 1) { L += __shfl_xor(L, d); V += __shfl_xor(V, d); }
  __shared__ float sL[16], sV[16];
  if ((t & 63) == 0) { sL[t >> 6] = L; sV[t >> 6] = V; }
  __syncthreads();
  if (t == 0) {
    float Ls = 0.f, Vs = 0.f;
#pragma unroll
    for (int i = 0; i < 16; ++i) { Ls += sL[i]; Vs += sV[i]; }
    out[0] = Ls / fmaxf(Vs, 1.f);
  }
}

extern "C" void kernel_launch(void* const* d_in, const int* in_sizes, int n_in,
                              void* d_out, int out_size, void* d_ws, size_t ws_size,
                              hipStream_t stream) {
  const float* hidden = (const float*)d_in[0];
  const int* labels = (const int*)d_in[1];
  float* out = (float*)d_out;
  char* w = (char*)d_ws;
  ushort* hsK     = (ushort*)(w);                  // 4 MB
  ushort* hs      = (ushort*)(w + 4194304);        // 4 MB
  float* dbuf     = (float*)(w + 8388608);         // 32 KB
  float* Cs       = (float*)(w + 8421376);         // 100 KB
  float* cntf     = (float*)(w + 8523776);         // 512 B
  float* rowseg   = (float*)(w + 8524288);         // 288 KB (64 x 9 x 128)
  float* colpart2 = (float*)(w + 8819200);         // 4 MB  (64 x 2 x 8192)
  float2* rl      = (float2*)(w + 13013504);       // 64 KB

  prep_kernel<<<2148, 256, 0, stream>>>(hidden, labels, hs, hsK, dbuf, Cs, cntf);
  main_kernel<<<256, 512, 0, stream>>>(hsK, rowseg, colpart2);
  rowloss_kernel<<<NB / 4, 256, 0, stream>>>(hs, labels, Cs, cntf, rowseg,
                                             colpart2, dbuf, rl);
  reduce_kernel<<<1, 1024, 0, stream>>>(rl, out);
}